// Round 3
// baseline (3488.520 us; speedup 1.0000x reference)
//
#include <hip/hip_runtime.h>

// PressureProjection on MI355X — round 9.
// R8 post-mortem: payload consolidation worked (bucket_place 565->354us,
// WRITE 461->245MB as predicted) but fused p-update regressed the CG loop:
// matvec gathered TWO arrays (p_old[src] + z[src]) -> 4MB gather set = whole
// per-XCD L2, thrashing vs the 64MB/iter payload stream, x20 iters (+700us).
// R9:
//  * CG restructured on the Az recurrence: Ap_j = Az_j + beta*Ap_{j-1}.
//    matvec gathers ONLY z (2MB, L2-resident); p/ap formed densely via
//    recurrence (ping-pong buffers). No separate p_update kernel.
//  * flux/diag accumulation moved to hist_flux (merged with bucket_hist):
//    coalesced ei/u_hat-gather/fn/fa/fd reads + 16M global f32 atomics into
//    interleaved {w,flux}[node]. Payload is now 8B {hi,w}: bucket_place
//    reads only ei/fa/fd (fetch ~190MB vs 730) and node_setup is dense.
//  * finalize in ORIGINAL edge order: coalesced fn reads (no 96MB random
//    eid-gather), phi[src] gather (2MB), 24M atomics into g[3N], dense out.
// Predicted: bucket_place ~70us, hist_flux ~150us, matvec ~20us/iter,
// total 2790 -> ~1500us. Falsifier: hist_flux >300us => atomic-throughput
// bound => move flux/diag back to bucketed pass.

#define TPB 256
#define TPB_A 1024
#define TPB_B 1024       // matvec: 1 thread per node in bucket
#define KB 2048          // grid for dense kernels & partial arrays
#define NBLK 512         // chunks for bucket sort (2 blocks/CU)
#define BSHIFT 10        // bucket = dst >> 10 (1024 nodes per bucket)
#define BSIZE 1024
#define MAXNB 512        // max coarse buckets (N <= 524288)
#define CG_ITERS 20
#define TOL2 1e-8f       // (CG_TOL=1e-4)^2

struct Sum3 { float a, b, c; };

// block-wide sums of three arrays (independent lengths), broadcast
template <int BS>
__device__ inline Sum3 block_sum3n_bcast(const float* __restrict__ A, int nA,
                                         const float* __restrict__ B, int nB,
                                         const float* __restrict__ C, int nC) {
  float va = 0.f, vb = 0.f, vc = 0.f;
  for (int k = threadIdx.x; k < nA; k += BS) va += A[k];
  for (int k = threadIdx.x; k < nB; k += BS) vb += B[k];
  for (int k = threadIdx.x; k < nC; k += BS) vc += C[k];
#pragma unroll
  for (int o = 32; o; o >>= 1) {
    va += __shfl_down(va, o, 64);
    vb += __shfl_down(vb, o, 64);
    vc += __shfl_down(vc, o, 64);
  }
  __shared__ float sa[BS / 64], sb[BS / 64], sc[BS / 64], bc[3];
  int lane = threadIdx.x & 63, wid = threadIdx.x >> 6;
  if (lane == 0) { sa[wid] = va; sb[wid] = vb; sc[wid] = vc; }
  __syncthreads();
  if (threadIdx.x == 0) {
    float ta = 0.f, tb = 0.f, tc = 0.f;
#pragma unroll
    for (int k = 0; k < BS / 64; k++) { ta += sa[k]; tb += sb[k]; tc += sc[k]; }
    bc[0] = ta; bc[1] = tb; bc[2] = tc;
  }
  __syncthreads();
  Sum3 r{bc[0], bc[1], bc[2]};
  __syncthreads();
  return r;
}

template <int BS>
__device__ inline void block_reduce1_store(float v1, float* d1) {
#pragma unroll
  for (int o = 32; o; o >>= 1) v1 += __shfl_down(v1, o, 64);
  __shared__ float s1[BS / 64];
  int lane = threadIdx.x & 63, wid = threadIdx.x >> 6;
  if (lane == 0) s1[wid] = v1;
  __syncthreads();
  if (threadIdx.x == 0) {
    float t1 = 0.f;
#pragma unroll
    for (int k = 0; k < BS / 64; k++) t1 += s1[k];
    *d1 = t1;
  }
}

template <int BS>
__device__ inline void block_reduce2_store(float v1, float v2, float* d1, float* d2) {
#pragma unroll
  for (int o = 32; o; o >>= 1) {
    v1 += __shfl_down(v1, o, 64);
    v2 += __shfl_down(v2, o, 64);
  }
  __shared__ float s1[BS / 64], s2[BS / 64];
  int lane = threadIdx.x & 63, wid = threadIdx.x >> 6;
  if (lane == 0) { s1[wid] = v1; s2[wid] = v2; }
  __syncthreads();
  if (threadIdx.x == 0) {
    float t1 = 0.f, t2 = 0.f;
#pragma unroll
    for (int k = 0; k < BS / 64; k++) { t1 += s1[k]; t2 += s2[k]; }
    *d1 = t1;
    *d2 = t2;
  }
}

// ---- zero the atomic accumulators (wb = interleaved {w,flux}, g = grad) ----
__global__ __launch_bounds__(TPB) void zero_accs(
    float* __restrict__ wb, float* __restrict__ g, int N) {
  int stride = gridDim.x * TPB;
  for (int i = blockIdx.x * TPB + threadIdx.x; i < 2 * N; i += stride) wb[i] = 0.f;
  for (int i = blockIdx.x * TPB + threadIdx.x; i < 3 * N; i += stride) g[i] = 0.f;
}

// ---- pass A0: histogram + flux/w accumulation (coalesced edge sweep) ----
__global__ __launch_bounds__(TPB_A) void hist_flux(
    const int* __restrict__ ei, const float* __restrict__ u_hat,
    const float* __restrict__ fn, const float* __restrict__ fa,
    const float* __restrict__ fd, unsigned* __restrict__ mat,
    float* __restrict__ wb, int E, int NB, int chunk) {
  __shared__ unsigned cntL[MAXNB];
  for (int i = threadIdx.x; i < NB; i += TPB_A) cntL[i] = 0;
  __syncthreads();
  int blk = blockIdx.x;
  int e0 = blk * chunk, e1 = min(E, e0 + chunk);
  for (int e = e0 + threadIdx.x; e < e1; e += TPB_A) {
    int s = ei[e], d = ei[E + e];
    float area = fa[e];
    float w = area / fmaxf(fd[e], 1e-8f);
    float ux = 0.5f * (u_hat[3 * s]     + u_hat[3 * d]);
    float uy = 0.5f * (u_hat[3 * s + 1] + u_hat[3 * d + 1]);
    float uz = 0.5f * (u_hat[3 * s + 2] + u_hat[3 * d + 2]);
    float flux = (ux * fn[3 * e] + uy * fn[3 * e + 1] + uz * fn[3 * e + 2]) * area;
    atomicAdd(&cntL[((unsigned)d) >> BSHIFT], 1u);
    atomicAdd(&wb[2 * d], w);
    atomicAdd(&wb[2 * d + 1], flux);
  }
  __syncthreads();
  for (int b = threadIdx.x; b < NB; b += TPB_A)
    mat[(size_t)b * NBLK + blk] = cntL[b];
}

// ---- scan (1024 elems / block) ----
__global__ __launch_bounds__(TPB) void scan_blocks(
    const unsigned* __restrict__ cnt, unsigned* __restrict__ offs,
    unsigned* __restrict__ btot, int n) {
  __shared__ unsigned sd[TPB];
  int t = threadIdx.x;
  int base = blockIdx.x * 1024 + t * 4;
  unsigned v0 = 0, v1 = 0, v2 = 0, v3 = 0;
  if (base + 0 < n) v0 = cnt[base + 0];
  if (base + 1 < n) v1 = cnt[base + 1];
  if (base + 2 < n) v2 = cnt[base + 2];
  if (base + 3 < n) v3 = cnt[base + 3];
  unsigned local = v0 + v1 + v2 + v3;
  sd[t] = local;
  __syncthreads();
  for (int o = 1; o < TPB; o <<= 1) {
    unsigned x = (t >= o) ? sd[t - o] : 0u;
    __syncthreads();
    sd[t] += x;
    __syncthreads();
  }
  unsigned excl = sd[t] - local;
  if (base + 0 < n) offs[base + 0] = excl; excl += v0;
  if (base + 1 < n) offs[base + 1] = excl; excl += v1;
  if (base + 2 < n) offs[base + 2] = excl; excl += v2;
  if (base + 3 < n) offs[base + 3] = excl;
  if (t == TPB - 1) btot[blockIdx.x] = sd[TPB - 1];
}

__global__ __launch_bounds__(512) void scan_totals(unsigned* __restrict__ btot, int nb) {
  __shared__ unsigned sd[512];
  int t = threadIdx.x;
  unsigned v = (t < nb) ? btot[t] : 0u;
  sd[t] = v;
  __syncthreads();
  for (int o = 1; o < 512; o <<= 1) {
    unsigned x = (t >= o) ? sd[t - o] : 0u;
    __syncthreads();
    sd[t] += x;
    __syncthreads();
  }
  if (t < nb) btot[t] = sd[t] - v;  // exclusive
}

__global__ __launch_bounds__(TPB) void scan_add(
    unsigned* __restrict__ offs, const unsigned* __restrict__ btot,
    int n, unsigned total) {
  int i = blockIdx.x * TPB + threadIdx.x;
  if (i < n) offs[i] += btot[i >> 10];
  if (i == 0) offs[n] = total;
}

// ---- pass A1: lean placement — 8-B payload {hi, w}; no fn/u_hat reads ----
__global__ __launch_bounds__(TPB_A) void bucket_place(
    const int* __restrict__ ei, const float* __restrict__ fa,
    const float* __restrict__ fd, const unsigned* __restrict__ offs,
    unsigned long long* __restrict__ A8, int E, int NB, int chunk) {
  __shared__ unsigned cntL[MAXNB];
  __shared__ unsigned offL[MAXNB];
  int blk = blockIdx.x;
  for (int i = threadIdx.x; i < NB; i += TPB_A) {
    cntL[i] = 0;
    offL[i] = offs[(size_t)i * NBLK + blk];
  }
  __syncthreads();
  int e0 = blk * chunk, e1 = min(E, e0 + chunk);
  for (int e = e0 + threadIdx.x; e < e1; e += TPB_A) {
    int s = ei[e], d = ei[E + e];
    float w = fa[e] / fmaxf(fd[e], 1e-8f);
    unsigned b = ((unsigned)d) >> BSHIFT;
    unsigned dl = ((unsigned)d) & (BSIZE - 1u);
    unsigned r = atomicAdd(&cntL[b], 1u);
    unsigned pos = offL[b] + r;
    unsigned hi = (dl << 19) | (unsigned)s;
    A8[(size_t)pos] = ((unsigned long long)hi << 32) |
                      (unsigned long long)__float_as_uint(w);
  }
}

// ---- CG setup: dense only (accumulators already hold wsum/fluxsum) ----
__global__ __launch_bounds__(TPB) void node_setup(
    const float* __restrict__ wb, const float* __restrict__ cv,
    float* __restrict__ diag, float* __restrict__ minv,
    float* __restrict__ r, float* __restrict__ z, float* __restrict__ phi,
    float* __restrict__ rz_part, float* __restrict__ rr_part, int N) {
  float rzv = 0.f, rrv = 0.f;
  for (int i = blockIdx.x * TPB + threadIdx.x; i < N; i += KB * TPB) {
    float wsum = wb[2 * i];
    float fsum = wb[2 * i + 1];
    float vol = fmaxf(cv[i], 1e-12f);
    float bval = fsum / vol;
    float mi = 1.0f / fmaxf(wsum, 1e-8f);
    diag[i] = wsum;
    minv[i] = mi;
    r[i] = bval;
    float zi = mi * bval;
    z[i] = zi;
    phi[i] = 0.f;
    rzv += bval * zi;
    rrv += bval * bval;
  }
  block_reduce2_store<TPB>(rzv, rrv, &rz_part[blockIdx.x], &rr_part[blockIdx.x]);
}

// ---- matvec on z: Az via bucketed gather; p/ap via recurrence (dense).
// p_j = z_j + beta*p_{j-1}; Ap_j = Az_j + beta*Ap_{j-1}. Gate on rr_j.
__global__ __launch_bounds__(TPB_B) void matvec_az(
    const float* __restrict__ z, const float* __restrict__ diag,
    const unsigned* __restrict__ offs, const unsigned long long* __restrict__ A8,
    const float* __restrict__ p_old, float* __restrict__ p_new,
    const float* __restrict__ ap_old, float* __restrict__ ap_new,
    float* __restrict__ pap_part,
    const float* __restrict__ rzJ_part, const float* __restrict__ rzJm1_part,
    const float* __restrict__ rrJ_part, int N, int first) {
  __shared__ float acc[TPB_B];
  int b = blockIdx.x;
  acc[threadIdx.x] = 0.f;
  __syncthreads();
  unsigned jb = offs[(size_t)b * NBLK], je = offs[(size_t)(b + 1) * NBLK];
  for (unsigned j = jb + threadIdx.x; j < je; j += TPB_B) {
    unsigned long long v = A8[(size_t)j];
    unsigned hi = (unsigned)(v >> 32);
    float w = __uint_as_float((unsigned)v);
    atomicAdd(&acc[hi >> 19], w * z[hi & 0x7FFFFu]);
  }
  __syncthreads();
  float beta = 0.f;
  bool act = true;
  if (!first) {
    Sum3 s = block_sum3n_bcast<TPB_B>(rzJ_part, KB, rzJm1_part, KB, rrJ_part, KB);
    act = (s.c >= TOL2);
    beta = s.a / (s.b + 1e-12f);
  }
  float contrib = 0.f;
  int node = (b << BSHIFT) + threadIdx.x;
  if (node < N) {
    float zi = z[node];
    float az = diag[node] * zi - acc[threadIdx.x];
    float pn, apn;
    if (first)    { pn = zi;                              apn = az; }
    else if (act) { pn = fmaf(beta, p_old[node], zi);     apn = fmaf(beta, ap_old[node], az); }
    else          { pn = p_old[node];                     apn = ap_old[node]; }
    p_new[node] = pn;
    ap_new[node] = apn;
    contrib = pn * apn;
  }
  block_reduce1_store<TPB_B>(contrib, &pap_part[b]);
}

// ---- gated phi/r update; writes z = minv*r; emits rz/rr partials ----
__global__ __launch_bounds__(TPB) void cg_update(
    float* __restrict__ phi, float* __restrict__ r, const float* __restrict__ p,
    const float* __restrict__ ap, const float* __restrict__ minv,
    float* __restrict__ z,
    const float* __restrict__ pap_it, const float* __restrict__ rz_it,
    const float* __restrict__ rr_it, float* __restrict__ rz_next,
    float* __restrict__ rr_next, int N, int NB) {
  Sum3 s = block_sum3n_bcast<TPB>(pap_it, NB, rz_it, KB, rr_it, KB);
  bool act = (s.c >= TOL2);
  float alpha = s.b / (s.a + 1e-12f);
  float rzacc = 0.f, rracc = 0.f;
  for (int i = blockIdx.x * TPB + threadIdx.x; i < N; i += KB * TPB) {
    float ri = r[i];
    if (act) {
      phi[i] += alpha * p[i];
      ri -= alpha * ap[i];
      r[i] = ri;
    }
    float zi = minv[i] * ri;
    z[i] = zi;
    rzacc += ri * zi;
    rracc += ri * ri;
  }
  block_reduce2_store<TPB>(rzacc, rracc, &rz_next[blockIdx.x], &rr_next[blockIdx.x]);
}

// ---- gradient accumulation in ORIGINAL edge order (coalesced fn reads) ----
__global__ __launch_bounds__(TPB) void finalize_grad(
    const int* __restrict__ ei, const float* __restrict__ fa,
    const float* __restrict__ fd, const float* __restrict__ fn,
    const float* __restrict__ phi, float* __restrict__ g, int E) {
  int stride = gridDim.x * TPB;
  for (int e = blockIdx.x * TPB + threadIdx.x; e < E; e += stride) {
    int s = ei[e], d = ei[E + e];
    float w = fa[e] / fmaxf(fd[e], 1e-8f);
    float t = w * phi[s];
    atomicAdd(&g[3 * d],     t * fn[3 * e]);
    atomicAdd(&g[3 * d + 1], t * fn[3 * e + 1]);
    atomicAdd(&g[3 * d + 2], t * fn[3 * e + 2]);
  }
}

// ---- dense output pass ----
__global__ __launch_bounds__(TPB) void final_out(
    const float* __restrict__ u_hat, const float* __restrict__ cv,
    const float* __restrict__ phi, const float* __restrict__ g,
    float* __restrict__ out, int N) {
  int stride = gridDim.x * TPB;
  for (int i = blockIdx.x * TPB + threadIdx.x; i < N; i += stride) {
    float iv = 1.0f / fmaxf(cv[i], 1e-12f);
    out[3 * i]     = u_hat[3 * i]     - g[3 * i]     * iv;
    out[3 * i + 1] = u_hat[3 * i + 1] - g[3 * i + 1] * iv;
    out[3 * i + 2] = u_hat[3 * i + 2] - g[3 * i + 2] * iv;
    out[3 * N + i] = phi[i];
  }
}

extern "C" void kernel_launch(void* const* d_in, const int* in_sizes, int n_in,
                              void* d_out, int out_size, void* d_ws, size_t ws_size,
                              hipStream_t stream) {
  const float* u_hat = (const float*)d_in[0];
  const int*   ei    = (const int*)d_in[1];
  const float* fn    = (const float*)d_in[2];
  const float* fa    = (const float*)d_in[3];
  const float* fd    = (const float*)d_in[4];
  const float* cv    = (const float*)d_in[5];
  float* out = (float*)d_out;

  const int N = in_sizes[0] / 3;   // 500,000
  const int E = in_sizes[1] / 2;   // 8,000,000
  const int NB = (N + BSIZE - 1) >> BSHIFT;  // coarse buckets (489)
  const int NS = NB * NBLK;        // scan length (250,368)
  const int chunk = (E + NBLK - 1) / NBLK;

  // ---- workspace bump allocator (256B aligned); ~95 MB ----
  char* base = (char*)d_ws;
  size_t off = 0;
  auto alloc = [&](size_t bytes) -> void* {
    void* ptr = base + off;
    off = (off + bytes + 255) & ~size_t(255);
    return ptr;
  };
  unsigned* mat   = (unsigned*)alloc((size_t)NS * 4);
  unsigned* offs  = (unsigned*)alloc((size_t)(NS + 1) * 4);
  unsigned* btot  = (unsigned*)alloc(512 * 4);
  float*    wb    = (float*)alloc((size_t)2 * N * 4);   // {w,flux} accum
  float*    g     = (float*)alloc((size_t)3 * N * 4);   // grad accum
  float*    diag  = (float*)alloc((size_t)N * 4);
  float*    minv  = (float*)alloc((size_t)N * 4);
  float*    phi   = (float*)alloc((size_t)N * 4);
  float*    rvec  = (float*)alloc((size_t)N * 4);
  float*    zvec  = (float*)alloc((size_t)N * 4);
  float*    pA    = (float*)alloc((size_t)N * 4);
  float*    pB    = (float*)alloc((size_t)N * 4);
  float*    apA   = (float*)alloc((size_t)N * 4);
  float*    apB   = (float*)alloc((size_t)N * 4);
  float*    rzrr  = (float*)alloc((size_t)(2 * (CG_ITERS + 1)) * KB * 4);
  float*    papp  = (float*)alloc((size_t)CG_ITERS * KB * 4);
  unsigned long long* A8 = (unsigned long long*)alloc((size_t)E * 8);
  (void)n_in; (void)out_size; (void)ws_size;

  auto rz_part = [&](int it) { return rzrr + (size_t)(2 * it) * KB; };
  auto rr_part = [&](int it) { return rzrr + (size_t)(2 * it + 1) * KB; };
  auto pap_part = [&](int it) { return papp + (size_t)it * KB; };

  const int nbScan = (NS + 1023) / 1024;          // 245 <= 512
  const int gridScanAdd = (NS + TPB - 1) / TPB;

  zero_accs<<<KB, TPB, 0, stream>>>(wb, g, N);

  hist_flux<<<NBLK, TPB_A, 0, stream>>>(ei, u_hat, fn, fa, fd, mat, wb,
                                        E, NB, chunk);

  scan_blocks<<<nbScan, TPB, 0, stream>>>(mat, offs, btot, NS);
  scan_totals<<<1, 512, 0, stream>>>(btot, nbScan);
  scan_add<<<gridScanAdd, TPB, 0, stream>>>(offs, btot, NS, (unsigned)E);

  bucket_place<<<NBLK, TPB_A, 0, stream>>>(ei, fa, fd, offs, A8, E, NB, chunk);

  node_setup<<<KB, TPB, 0, stream>>>(wb, cv, diag, minv, rvec, zvec, phi,
                                     rz_part(0), rr_part(0), N);

  float* pbuf[2]  = {pA, pB};
  float* apbuf[2] = {apA, apB};
  for (int it = 0; it < CG_ITERS; it++) {
    int ni = it & 1;                 // new buffer index
    float* pn  = pbuf[ni];
    float* apn = apbuf[ni];
    const float* po  = pbuf[1 - ni];
    const float* apo = apbuf[1 - ni];
    int first = (it == 0) ? 1 : 0;
    matvec_az<<<NB, TPB_B, 0, stream>>>(zvec, diag, offs, A8,
                                        po, pn, apo, apn, pap_part(it),
                                        rz_part(it), rz_part(it > 0 ? it - 1 : 0),
                                        rr_part(it), N, first);
    cg_update<<<KB, TPB, 0, stream>>>(phi, rvec, pn, apn, minv, zvec,
                                      pap_part(it), rz_part(it), rr_part(it),
                                      rz_part(it + 1), rr_part(it + 1), N, NB);
  }

  finalize_grad<<<KB, TPB, 0, stream>>>(ei, fa, fd, fn, phi, g, E);
  final_out<<<KB, TPB, 0, stream>>>(u_hat, cv, phi, g, out, N);
}

// Round 4
// 2164.721 us; speedup vs baseline: 1.6115x; 1.6115x over previous
//
#include <hip/hip_runtime.h>

// PressureProjection on MI355X — round 10.
// R9 post-mortem: global-memory f32 atomic scatter is a dead end
// (finalize_grad 1182us, 750MB WRITE for a 6MB accumulator; hist_flux
// similar). LDS-bucketed accumulation (R6/R8) is the right structure.
// R8 counter re-read: place FETCH 730MB vs 236MB input -> ~500MB RFO
// refetch on scattered payload stores, amplified by streaming-read
// eviction of half-filled lines.
// R10 recomposition (all pieces individually validated):
//  * hist pass precomputes WF[e]={w,flux} (coalesced, no atomics);
//    bucket_place then reads only ei+WF (128MB streaming) -> RFO collapse.
//  * CG on the Az recurrence (R9): matvec gathers ONLY z (2MB, L2);
//    p/ap via dense recurrence; A8 hot stream read nontemporally so the
//    64MB/iter payload stream doesn't thrash z out of L2.
//  * node_setup bucketed (R8): LDS wsum/flux accumulate + A8 split.
//  * finalize bucketed (R8): LDS grad accumulate, fn via eid (L3-resident).
// Workspace tiers: base 148MB (proven fits), +A8 @212MB, +WF @276MB;
// null-pointer fallbacks keep every tier correct.
// Predicted: finalize 1182->~150us, place FETCH 730->~280MB dur ~180us,
// hist ~100us, matvec ~25us/iter -> total ~1500-1700us.

#define TPB 256
#define TPB_A 1024
#define TPB_B 1024       // bucket kernels: 1 thread per node in bucket
#define KB 2048          // grid for dense kernels & partial arrays
#define NBLK 256         // chunks for bucket sort
#define BSHIFT 10        // bucket = dst >> 10 (1024 nodes per bucket)
#define BSIZE 1024
#define MAXNB 512        // max coarse buckets (N <= 524288)
#define CG_ITERS 20
#define TOL2 1e-8f       // (CG_TOL=1e-4)^2

typedef unsigned long long ull;

struct Sum3 { float a, b, c; };

// block-wide sums of three arrays (independent lengths), broadcast
template <int BS>
__device__ inline Sum3 block_sum3n_bcast(const float* __restrict__ A, int nA,
                                         const float* __restrict__ B, int nB,
                                         const float* __restrict__ C, int nC) {
  float va = 0.f, vb = 0.f, vc = 0.f;
  for (int k = threadIdx.x; k < nA; k += BS) va += A[k];
  for (int k = threadIdx.x; k < nB; k += BS) vb += B[k];
  for (int k = threadIdx.x; k < nC; k += BS) vc += C[k];
#pragma unroll
  for (int o = 32; o; o >>= 1) {
    va += __shfl_down(va, o, 64);
    vb += __shfl_down(vb, o, 64);
    vc += __shfl_down(vc, o, 64);
  }
  __shared__ float sa[BS / 64], sb[BS / 64], sc[BS / 64], bc[3];
  int lane = threadIdx.x & 63, wid = threadIdx.x >> 6;
  if (lane == 0) { sa[wid] = va; sb[wid] = vb; sc[wid] = vc; }
  __syncthreads();
  if (threadIdx.x == 0) {
    float ta = 0.f, tb = 0.f, tc = 0.f;
#pragma unroll
    for (int k = 0; k < BS / 64; k++) { ta += sa[k]; tb += sb[k]; tc += sc[k]; }
    bc[0] = ta; bc[1] = tb; bc[2] = tc;
  }
  __syncthreads();
  Sum3 r{bc[0], bc[1], bc[2]};
  __syncthreads();
  return r;
}

template <int BS>
__device__ inline void block_reduce1_store(float v1, float* d1) {
#pragma unroll
  for (int o = 32; o; o >>= 1) v1 += __shfl_down(v1, o, 64);
  __shared__ float s1[BS / 64];
  int lane = threadIdx.x & 63, wid = threadIdx.x >> 6;
  if (lane == 0) s1[wid] = v1;
  __syncthreads();
  if (threadIdx.x == 0) {
    float t1 = 0.f;
#pragma unroll
    for (int k = 0; k < BS / 64; k++) t1 += s1[k];
    *d1 = t1;
  }
}

template <int BS>
__device__ inline void block_reduce2_store(float v1, float v2, float* d1, float* d2) {
#pragma unroll
  for (int o = 32; o; o >>= 1) {
    v1 += __shfl_down(v1, o, 64);
    v2 += __shfl_down(v2, o, 64);
  }
  __shared__ float s1[BS / 64], s2[BS / 64];
  int lane = threadIdx.x & 63, wid = threadIdx.x >> 6;
  if (lane == 0) { s1[wid] = v1; s2[wid] = v2; }
  __syncthreads();
  if (threadIdx.x == 0) {
    float t1 = 0.f, t2 = 0.f;
#pragma unroll
    for (int k = 0; k < BS / 64; k++) { t1 += s1[k]; t2 += s2[k]; }
    *d1 = t1;
    *d2 = t2;
  }
}

// ---- pass A0: LDS histogram (+ optional coalesced WF={w,flux} write) ----
__global__ __launch_bounds__(TPB_A) void hist_wf(
    const int* __restrict__ ei, const float* __restrict__ u_hat,
    const float* __restrict__ fn, const float* __restrict__ fa,
    const float* __restrict__ fd, unsigned* __restrict__ mat,
    float2* __restrict__ wf, int E, int NB, int chunk) {
  __shared__ unsigned cntL[MAXNB];
  for (int i = threadIdx.x; i < NB; i += TPB_A) cntL[i] = 0;
  __syncthreads();
  int blk = blockIdx.x;
  int e0 = blk * chunk, e1 = min(E, e0 + chunk);
  for (int e = e0 + threadIdx.x; e < e1; e += TPB_A) {
    int d = ei[E + e];
    atomicAdd(&cntL[((unsigned)d) >> BSHIFT], 1u);
    if (wf) {
      int s = ei[e];
      float area = fa[e];
      float w = area / fmaxf(fd[e], 1e-8f);
      float ux = 0.5f * (u_hat[3 * s]     + u_hat[3 * d]);
      float uy = 0.5f * (u_hat[3 * s + 1] + u_hat[3 * d + 1]);
      float uz = 0.5f * (u_hat[3 * s + 2] + u_hat[3 * d + 2]);
      float flux = (ux * fn[3 * e] + uy * fn[3 * e + 1] + uz * fn[3 * e + 2]) * area;
      wf[e] = make_float2(w, flux);
    }
  }
  __syncthreads();
  for (int b = threadIdx.x; b < NB; b += TPB_A)
    mat[(size_t)b * NBLK + blk] = cntL[b];
}

// ---- scan (1024 elems / block) ----
__global__ __launch_bounds__(TPB) void scan_blocks(
    const unsigned* __restrict__ cnt, unsigned* __restrict__ offs,
    unsigned* __restrict__ btot, int n) {
  __shared__ unsigned sd[TPB];
  int t = threadIdx.x;
  int base = blockIdx.x * 1024 + t * 4;
  unsigned v0 = 0, v1 = 0, v2 = 0, v3 = 0;
  if (base + 0 < n) v0 = cnt[base + 0];
  if (base + 1 < n) v1 = cnt[base + 1];
  if (base + 2 < n) v2 = cnt[base + 2];
  if (base + 3 < n) v3 = cnt[base + 3];
  unsigned local = v0 + v1 + v2 + v3;
  sd[t] = local;
  __syncthreads();
  for (int o = 1; o < TPB; o <<= 1) {
    unsigned x = (t >= o) ? sd[t - o] : 0u;
    __syncthreads();
    sd[t] += x;
    __syncthreads();
  }
  unsigned excl = sd[t] - local;
  if (base + 0 < n) offs[base + 0] = excl; excl += v0;
  if (base + 1 < n) offs[base + 1] = excl; excl += v1;
  if (base + 2 < n) offs[base + 2] = excl; excl += v2;
  if (base + 3 < n) offs[base + 3] = excl;
  if (t == TPB - 1) btot[blockIdx.x] = sd[TPB - 1];
}

__global__ __launch_bounds__(512) void scan_totals(unsigned* __restrict__ btot, int nb) {
  __shared__ unsigned sd[512];
  int t = threadIdx.x;
  unsigned v = (t < nb) ? btot[t] : 0u;
  sd[t] = v;
  __syncthreads();
  for (int o = 1; o < 512; o <<= 1) {
    unsigned x = (t >= o) ? sd[t - o] : 0u;
    __syncthreads();
    sd[t] += x;
    __syncthreads();
  }
  if (t < nb) btot[t] = sd[t] - v;  // exclusive
}

__global__ __launch_bounds__(TPB) void scan_add(
    unsigned* __restrict__ offs, const unsigned* __restrict__ btot,
    int n, unsigned total) {
  int i = blockIdx.x * TPB + threadIdx.x;
  if (i < n) offs[i] += btot[i >> 10];
  if (i == 0) offs[n] = total;
}

// ---- pass A1: place edges as 16-B {hi, w, flux, eid}.
// With WF: reads only ei+WF (lean streaming -> minimal RFO eviction).
__global__ __launch_bounds__(TPB_A) void bucket_place(
    const int* __restrict__ ei, const float* __restrict__ u_hat,
    const float* __restrict__ fn, const float* __restrict__ fa,
    const float* __restrict__ fd, const float2* __restrict__ wf,
    const unsigned* __restrict__ offs, uint4* __restrict__ A16,
    int E, int NB, int chunk) {
  __shared__ unsigned cntL[MAXNB];
  __shared__ unsigned offL[MAXNB];
  int blk = blockIdx.x;
  for (int i = threadIdx.x; i < NB; i += TPB_A) {
    cntL[i] = 0;
    offL[i] = offs[(size_t)i * NBLK + blk];
  }
  __syncthreads();
  int e0 = blk * chunk, e1 = min(E, e0 + chunk);
  for (int e = e0 + threadIdx.x; e < e1; e += TPB_A) {
    int s = ei[e], d = ei[E + e];
    float w, flux;
    if (wf) {
      float2 v = wf[e];
      w = v.x; flux = v.y;
    } else {
      float area = fa[e];
      w = area / fmaxf(fd[e], 1e-8f);
      float ux = 0.5f * (u_hat[3 * s]     + u_hat[3 * d]);
      float uy = 0.5f * (u_hat[3 * s + 1] + u_hat[3 * d + 1]);
      float uz = 0.5f * (u_hat[3 * s + 2] + u_hat[3 * d + 2]);
      flux = (ux * fn[3 * e] + uy * fn[3 * e + 1] + uz * fn[3 * e + 2]) * area;
    }
    unsigned b = ((unsigned)d) >> BSHIFT;
    unsigned dl = ((unsigned)d) & (BSIZE - 1u);
    unsigned r = atomicAdd(&cntL[b], 1u);
    unsigned pos = offL[b] + r;
    unsigned hi = (dl << 19) | (unsigned)s;
    A16[(size_t)pos] = make_uint4(hi, __float_as_uint(w),
                                  __float_as_uint(flux), (unsigned)e);
  }
}

// ---- CG setup: per-bucket LDS sums of w and flux; splits hot A8 stream ----
__global__ __launch_bounds__(TPB_B) void node_setup(
    const uint4* __restrict__ A16, ull* __restrict__ A8,
    const unsigned* __restrict__ offs, const float* __restrict__ cv,
    float* __restrict__ diag, float* __restrict__ minv,
    float* __restrict__ r, float* __restrict__ z, float* __restrict__ phi,
    float* __restrict__ rz_part, float* __restrict__ rr_part, int N, int NB) {
  __shared__ float wacc[TPB_B], facc[TPB_B];
  int b = blockIdx.x;
  float rzv = 0.f, rrv = 0.f;
  if (b < NB) {
    wacc[threadIdx.x] = 0.f;
    facc[threadIdx.x] = 0.f;
    __syncthreads();
    unsigned jb = offs[(size_t)b * NBLK], je = offs[(size_t)(b + 1) * NBLK];
    const ull* q = (const ull*)A16;
    for (unsigned j = jb + threadIdx.x; j < je; j += TPB_B) {
      ull a = __builtin_nontemporal_load(&q[(size_t)2 * j]);      // {hi, w}
      ull bq = __builtin_nontemporal_load(&q[(size_t)2 * j + 1]); // {flux, eid}
      unsigned hi = (unsigned)a;
      float w = __uint_as_float((unsigned)(a >> 32));
      float flux = __uint_as_float((unsigned)bq);
      atomicAdd(&wacc[hi >> 19], w);
      atomicAdd(&facc[hi >> 19], flux);
      if (A8) A8[(size_t)j] = a;  // sequential 8-B hot stream {hi,w}
    }
    __syncthreads();
    int node = (b << BSHIFT) + threadIdx.x;
    if (node < N) {
      float wsum = wacc[threadIdx.x];
      float vol = fmaxf(cv[node], 1e-12f);
      float bval = facc[threadIdx.x] / vol;
      float mi = 1.0f / fmaxf(wsum, 1e-8f);
      diag[node] = wsum;
      minv[node] = mi;
      r[node] = bval;
      float zi = mi * bval;
      z[node] = zi;
      phi[node] = 0.f;
      rzv = bval * zi;
      rrv = bval * bval;
    }
  }
  block_reduce2_store<TPB_B>(rzv, rrv, &rz_part[blockIdx.x], &rr_part[blockIdx.x]);
}

// ---- matvec on z: Az via bucketed gather; p/ap via recurrence (dense).
// p_j = z_j + beta*p_{j-1}; Ap_j = Az_j + beta*Ap_{j-1}. Gate on rr_j.
__global__ __launch_bounds__(TPB_B) void matvec_az(
    const float* __restrict__ z, const float* __restrict__ diag,
    const unsigned* __restrict__ offs, const ull* __restrict__ A8,
    const uint4* __restrict__ A16,
    const float* __restrict__ p_old, float* __restrict__ p_new,
    const float* __restrict__ ap_old, float* __restrict__ ap_new,
    float* __restrict__ pap_part,
    const float* __restrict__ rzJ_part, const float* __restrict__ rzJm1_part,
    const float* __restrict__ rrJ_part, int N, int first) {
  __shared__ float acc[TPB_B];
  int b = blockIdx.x;
  acc[threadIdx.x] = 0.f;
  __syncthreads();
  unsigned jb = offs[(size_t)b * NBLK], je = offs[(size_t)(b + 1) * NBLK];
  if (A8) {
    for (unsigned j = jb + threadIdx.x; j < je; j += TPB_B) {
      ull v = __builtin_nontemporal_load(&A8[(size_t)j]);
      unsigned hi = (unsigned)v;
      float w = __uint_as_float((unsigned)(v >> 32));
      atomicAdd(&acc[hi >> 19], w * z[hi & 0x7FFFFu]);
    }
  } else {
    const ull* q = (const ull*)A16;
    for (unsigned j = jb + threadIdx.x; j < je; j += TPB_B) {
      ull v = __builtin_nontemporal_load(&q[(size_t)2 * j]);
      unsigned hi = (unsigned)v;
      float w = __uint_as_float((unsigned)(v >> 32));
      atomicAdd(&acc[hi >> 19], w * z[hi & 0x7FFFFu]);
    }
  }
  __syncthreads();
  float beta = 0.f;
  bool act = true;
  if (!first) {
    Sum3 s = block_sum3n_bcast<TPB_B>(rzJ_part, KB, rzJm1_part, KB, rrJ_part, KB);
    act = (s.c >= TOL2);
    beta = s.a / (s.b + 1e-12f);
  }
  float contrib = 0.f;
  int node = (b << BSHIFT) + threadIdx.x;
  if (node < N) {
    float zi = z[node];
    float az = diag[node] * zi - acc[threadIdx.x];
    float pn, apn;
    if (first)    { pn = zi;                          apn = az; }
    else if (act) { pn = fmaf(beta, p_old[node], zi); apn = fmaf(beta, ap_old[node], az); }
    else          { pn = p_old[node];                 apn = ap_old[node]; }
    p_new[node] = pn;
    ap_new[node] = apn;
    contrib = pn * apn;
  }
  block_reduce1_store<TPB_B>(contrib, &pap_part[b]);
}

// ---- gated phi/r update; writes z = minv*r; emits rz/rr partials ----
__global__ __launch_bounds__(TPB) void cg_update(
    float* __restrict__ phi, float* __restrict__ r, const float* __restrict__ p,
    const float* __restrict__ ap, const float* __restrict__ minv,
    float* __restrict__ z,
    const float* __restrict__ pap_it, const float* __restrict__ rz_it,
    const float* __restrict__ rr_it, float* __restrict__ rz_next,
    float* __restrict__ rr_next, int N, int NB) {
  Sum3 s = block_sum3n_bcast<TPB>(pap_it, NB, rz_it, KB, rr_it, KB);
  bool act = (s.c >= TOL2);
  float alpha = s.b / (s.a + 1e-12f);
  float rzacc = 0.f, rracc = 0.f;
  for (int i = blockIdx.x * TPB + threadIdx.x; i < N; i += KB * TPB) {
    float ri = r[i];
    if (act) {
      phi[i] += alpha * p[i];
      ri -= alpha * ap[i];
      r[i] = ri;
    }
    float zi = minv[i] * ri;
    z[i] = zi;
    rzacc += ri * zi;
    rracc += ri * ri;
  }
  block_reduce2_store<TPB>(rzacc, rracc, &rz_next[blockIdx.x], &rr_next[blockIdx.x]);
}

// ---- pressure correction + output: per-bucket LDS grad accumulate ----
__global__ __launch_bounds__(TPB_B) void finalize(
    const float* __restrict__ u_hat, const float* __restrict__ cv,
    const float* __restrict__ phi, const unsigned* __restrict__ offs,
    const uint4* __restrict__ A16, const float* __restrict__ fn,
    float* __restrict__ out, int N, int NB) {
  __shared__ float gxa[TPB_B], gya[TPB_B], gza[TPB_B];
  int b = blockIdx.x;
  if (b >= NB) return;
  gxa[threadIdx.x] = 0.f;
  gya[threadIdx.x] = 0.f;
  gza[threadIdx.x] = 0.f;
  __syncthreads();
  unsigned jb = offs[(size_t)b * NBLK], je = offs[(size_t)(b + 1) * NBLK];
  const ull* q = (const ull*)A16;
  for (unsigned j = jb + threadIdx.x; j < je; j += TPB_B) {
    ull a = __builtin_nontemporal_load(&q[(size_t)2 * j]);      // {hi, w}
    ull bq = __builtin_nontemporal_load(&q[(size_t)2 * j + 1]); // {flux, eid}
    unsigned hi = (unsigned)a;
    float w = __uint_as_float((unsigned)(a >> 32));
    int e = (int)(unsigned)(bq >> 32);
    float t = w * phi[hi & 0x7FFFFu];
    int dl = hi >> 19;
    atomicAdd(&gxa[dl], t * fn[3 * e]);
    atomicAdd(&gya[dl], t * fn[3 * e + 1]);
    atomicAdd(&gza[dl], t * fn[3 * e + 2]);
  }
  __syncthreads();
  int node = (b << BSHIFT) + threadIdx.x;
  if (node < N) {
    float iv = 1.0f / fmaxf(cv[node], 1e-12f);
    out[3 * node]     = u_hat[3 * node]     - gxa[threadIdx.x] * iv;
    out[3 * node + 1] = u_hat[3 * node + 1] - gya[threadIdx.x] * iv;
    out[3 * node + 2] = u_hat[3 * node + 2] - gza[threadIdx.x] * iv;
    out[3 * N + node] = phi[node];
  }
}

extern "C" void kernel_launch(void* const* d_in, const int* in_sizes, int n_in,
                              void* d_out, int out_size, void* d_ws, size_t ws_size,
                              hipStream_t stream) {
  const float* u_hat = (const float*)d_in[0];
  const int*   ei    = (const int*)d_in[1];
  const float* fn    = (const float*)d_in[2];
  const float* fa    = (const float*)d_in[3];
  const float* fd    = (const float*)d_in[4];
  const float* cv    = (const float*)d_in[5];
  float* out = (float*)d_out;

  const int N = in_sizes[0] / 3;   // 500,000
  const int E = in_sizes[1] / 2;   // 8,000,000
  const int NB = (N + BSIZE - 1) >> BSHIFT;  // coarse buckets (489)
  const int NS = NB * NBLK;        // scan length (125,184)
  const int chunk = (E + NBLK - 1) / NBLK;

  // ---- workspace bump allocator (256B aligned) ----
  char* base = (char*)d_ws;
  size_t off = 0;
  auto alloc = [&](size_t bytes) -> void* {
    void* ptr = base + off;
    off = (off + bytes + 255) & ~size_t(255);
    return ptr;
  };
  unsigned* mat   = (unsigned*)alloc((size_t)NS * 4);
  unsigned* offs  = (unsigned*)alloc((size_t)(NS + 1) * 4);
  unsigned* btot  = (unsigned*)alloc(512 * 4);
  float*    diag  = (float*)alloc((size_t)N * 4);
  float*    minv  = (float*)alloc((size_t)N * 4);
  float*    phi   = (float*)alloc((size_t)N * 4);
  float*    rvec  = (float*)alloc((size_t)N * 4);
  float*    zvec  = (float*)alloc((size_t)N * 4);
  float*    pA    = (float*)alloc((size_t)N * 4);
  float*    pB    = (float*)alloc((size_t)N * 4);
  float*    apA   = (float*)alloc((size_t)N * 4);
  float*    apB   = (float*)alloc((size_t)N * 4);
  float*    rzrr  = (float*)alloc((size_t)(2 * (CG_ITERS + 1)) * KB * 4);
  float*    papp  = (float*)alloc((size_t)CG_ITERS * KB * 4);
  uint4*    A16   = (uint4*)alloc((size_t)E * 16);      // base ≈ 148 MB (proven)
  ull* A8 = nullptr;                                    // tier 1: +64 MB
  if (off + (size_t)E * 8 + 256 <= ws_size) A8 = (ull*)alloc((size_t)E * 8);
  float2* WF = nullptr;                                 // tier 2: +64 MB
  if (off + (size_t)E * 8 + 256 <= ws_size) WF = (float2*)alloc((size_t)E * 8);
  (void)n_in; (void)out_size;

  auto rz_part = [&](int it) { return rzrr + (size_t)(2 * it) * KB; };
  auto rr_part = [&](int it) { return rzrr + (size_t)(2 * it + 1) * KB; };
  auto pap_part = [&](int it) { return papp + (size_t)it * KB; };

  const int nbScan = (NS + 1023) / 1024;          // 123 <= 512
  const int gridScanAdd = (NS + TPB - 1) / TPB;

  hist_wf<<<NBLK, TPB_A, 0, stream>>>(ei, u_hat, fn, fa, fd, mat, WF,
                                      E, NB, chunk);

  scan_blocks<<<nbScan, TPB, 0, stream>>>(mat, offs, btot, NS);
  scan_totals<<<1, 512, 0, stream>>>(btot, nbScan);
  scan_add<<<gridScanAdd, TPB, 0, stream>>>(offs, btot, NS, (unsigned)E);

  bucket_place<<<NBLK, TPB_A, 0, stream>>>(ei, u_hat, fn, fa, fd, WF, offs,
                                           A16, E, NB, chunk);

  node_setup<<<KB, TPB_B, 0, stream>>>(A16, A8, offs, cv, diag, minv,
                                       rvec, zvec, phi,
                                       rz_part(0), rr_part(0), N, NB);

  float* pbuf[2]  = {pA, pB};
  float* apbuf[2] = {apA, apB};
  for (int it = 0; it < CG_ITERS; it++) {
    int ni = it & 1;                 // new buffer index
    float* pn  = pbuf[ni];
    float* apn = apbuf[ni];
    const float* po  = pbuf[1 - ni];
    const float* apo = apbuf[1 - ni];
    int first = (it == 0) ? 1 : 0;
    matvec_az<<<NB, TPB_B, 0, stream>>>(zvec, diag, offs, A8, A16,
                                        po, pn, apo, apn, pap_part(it),
                                        rz_part(it), rz_part(it > 0 ? it - 1 : 0),
                                        rr_part(it), N, first);
    cg_update<<<KB, TPB, 0, stream>>>(phi, rvec, pn, apn, minv, zvec,
                                      pap_part(it), rz_part(it), rr_part(it),
                                      rz_part(it + 1), rr_part(it + 1), N, NB);
  }

  finalize<<<NB, TPB_B, 0, stream>>>(u_hat, cv, phi, offs, A16,
                                     fn, out, N, NB);
}